// Round 4
// baseline (257.660 us; speedup 1.0000x reference)
//
#include <hip/hip_runtime.h>
#include <hip/hip_bf16.h>
#include <math.h>
#include <stdint.h>

#ifndef M_PI
#define M_PI 3.14159265358979323846
#endif

#define S_    128
#define B_    128
#define E_    64
#define H_    8
#define NQ_   8
#define T_    12
#define FAN_  72          // E_ + H_
#define NOPS_ 30

// ---------------------------------------------------------------------------
// Host-side: numpy.random.RandomState(1234) legacy stream.
// randint(n), n-1 < 2^32: single 32-bit masked-rejection draws.
// uniform(lo,hi): rk_double = (a>>5)*2^26 + (b>>6), /2^53, a drawn first.
// ---------------------------------------------------------------------------
struct MT19937 {
    uint32_t mt[624];
    int idx;
    void seed(uint32_t s) {
        for (int i = 0; i < 624; i++) {
            mt[i] = s;
            s = 1812433253u * (s ^ (s >> 30)) + (uint32_t)i + 1u;
        }
        idx = 624;
    }
    uint32_t next() {
        if (idx >= 624) {
            for (int i = 0; i < 624; i++) {
                uint32_t y = (mt[i] & 0x80000000u) | (mt[(i + 1) % 624] & 0x7fffffffu);
                uint32_t v = mt[(i + 397) % 624] ^ (y >> 1);
                mt[i] = (y & 1u) ? (v ^ 0x9908b0dfu) : v;
            }
            idx = 0;
        }
        uint32_t y = mt[idx++];
        y ^= y >> 11;
        y ^= (y << 7)  & 0x9d2c5680u;
        y ^= (y << 15) & 0xefc60000u;
        y ^= y >> 18;
        return y;
    }
    uint32_t randint(uint32_t n) {
        uint32_t rng = n - 1u;
        uint32_t mask = rng;
        mask |= mask >> 1; mask |= mask >> 2; mask |= mask >> 4;
        mask |= mask >> 8; mask |= mask >> 16;
        uint32_t v;
        do { v = next() & mask; } while (v > rng);
        return v;
    }
    double uniform(double lo, double hi) {
        uint32_t a = next() >> 5, b = next() >> 6;
        double d = ((double)a * 67108864.0 + (double)b) / 9007199254740992.0;
        return lo + (hi - lo) * d;
    }
};

// op types: 0=rx, 1=ry, 2=rz, 3=cnot
struct QOps {
    int   type[NOPS_];
    int   w1[NOPS_];   // wire (rot) or control (cnot)
    int   w2[NOPS_];   // target (cnot)
    float c0[NOPS_];   // cos(th/2)   (rz: pr =  cos(th/2))
    float c1[NOPS_];   // sin(th/2)   (rz: pi = -sin(th/2))
};

static QOps make_ops() {
    MT19937 rng;
    rng.seed(1234u);
    QOps o;
    for (int i = 0; i < NOPS_; i++) {
        uint32_t kind = rng.randint(4);
        if (kind == 3u) {
            int c = (int)rng.randint(8);
            int t = (int)rng.randint(7);
            if (t >= c) t += 1;
            o.type[i] = 3; o.w1[i] = c; o.w2[i] = t;
            o.c0[i] = 0.f; o.c1[i] = 0.f;
        } else {
            int g = (int)(kind % 3u);            // 0 rx, 1 ry, 2 rz
            int w = (int)rng.randint(8);
            double th = rng.uniform(0.0, 2.0 * M_PI);
            double hh = 0.5 * th;
            o.type[i] = g; o.w1[i] = w; o.w2[i] = -1;
            o.c0[i] = (float)cos(hh);
            o.c1[i] = (g == 2) ? (float)(-sin(hh)) : (float)sin(hh);
        }
    }
    return o;
}

// ---------------------------------------------------------------------------
// Device helpers
// ---------------------------------------------------------------------------
__device__ __forceinline__ float sigmoid_f(float x) { return 1.f / (1.f + __expf(-x)); }
__device__ __forceinline__ float tanh_f(float x) {
    float e = __expf(2.f * x);
    return 1.f - 2.f / (e + 1.f);
}

// Wire w -> bit of amp index G = lane*4 + j (G bit7..0 = wire0..7):
// w<6: lane bit (5-w); w==6: j bit1; w==7: j bit0.
__device__ __forceinline__ int qbit(int w, int lane, int j) {
    if (w < 6) return (lane >> (5 - w)) & 1;
    if (w == 6) return (j >> 1) & 1;
    return j & 1;
}

__device__ __forceinline__ void gate2(int ty, float c, float s,
    float& a0r, float& a0i, float& a1r, float& a1i)
{
    if (ty == 0) {  // rx
        float n0r = c * a0r + s * a1i;
        float n0i = c * a0i - s * a1r;
        float n1r = c * a1r + s * a0i;
        float n1i = c * a1i - s * a0r;
        a0r = n0r; a0i = n0i; a1r = n1r; a1i = n1i;
    } else {        // ry
        float n0r = c * a0r - s * a1r;
        float n0i = c * a0i - s * a1i;
        float n1r = s * a0r + c * a1r;
        float n1i = s * a0i + c * a1i;
        a0r = n0r; a0i = n0i; a1r = n1r; a1i = n1i;
    }
}

__device__ __forceinline__ void apply_rot_any(int ty, int w, float c, float s,
    int lane, float ar[4], float ai[4])
{
    if (w < 6) {
        int m   = 1 << (5 - w);
        int bit = (lane >> (5 - w)) & 1;
        float sg = bit ? s : -s;
        #pragma unroll
        for (int j = 0; j < 4; j++) {
            float br = __shfl_xor(ar[j], m, 64);
            float bi = __shfl_xor(ai[j], m, 64);
            if (ty == 0) {  // rx (bit-symmetric)
                float nr = c * ar[j] + s * bi;
                float ni = c * ai[j] - s * br;
                ar[j] = nr; ai[j] = ni;
            } else {        // ry
                ar[j] = c * ar[j] + sg * br;
                ai[j] = c * ai[j] + sg * bi;
            }
        }
    } else if (w == 6) {
        gate2(ty, c, s, ar[0], ai[0], ar[2], ai[2]);
        gate2(ty, c, s, ar[1], ai[1], ar[3], ai[3]);
    } else {
        gate2(ty, c, s, ar[0], ai[0], ar[1], ai[1]);
        gate2(ty, c, s, ar[2], ai[2], ar[3], ai[3]);
    }
}

__device__ __forceinline__ void apply_rz(int w, float pr, float pi,
    int lane, float ar[4], float ai[4])
{
    #pragma unroll
    for (int j = 0; j < 4; j++) {
        int bit = qbit(w, lane, j);
        float e = bit ? -pi : pi;
        float nr = ar[j] * pr - ai[j] * e;
        float ni = ar[j] * e + ai[j] * pr;
        ar[j] = nr; ai[j] = ni;
    }
}

__device__ __forceinline__ void apply_cnot(int cw, int tw, int lane,
    float ar[4], float ai[4])
{
    if (tw < 6) {
        int m = 1 << (5 - tw);
        #pragma unroll
        for (int j = 0; j < 4; j++) {
            float br = __shfl_xor(ar[j], m, 64);
            float bi = __shfl_xor(ai[j], m, 64);
            int ctrl = qbit(cw, lane, j);
            ar[j] = ctrl ? br : ar[j];
            ai[j] = ctrl ? bi : ai[j];
        }
    } else if (tw == 6) {   // swap pairs (0,2),(1,3) under control
        int cA = qbit(cw, lane, 0);
        int cB = qbit(cw, lane, 1);
        float n0r = cA ? ar[2] : ar[0], n0i = cA ? ai[2] : ai[0];
        float n2r = cA ? ar[0] : ar[2], n2i = cA ? ai[0] : ai[2];
        float n1r = cB ? ar[3] : ar[1], n1i = cB ? ai[3] : ai[1];
        float n3r = cB ? ar[1] : ar[3], n3i = cB ? ai[1] : ai[3];
        ar[0] = n0r; ai[0] = n0i; ar[1] = n1r; ai[1] = n1i;
        ar[2] = n2r; ai[2] = n2i; ar[3] = n3r; ai[3] = n3i;
    } else {                // swap pairs (0,1),(2,3) under control
        int cA = qbit(cw, lane, 0);
        int cB = qbit(cw, lane, 2);
        float n0r = cA ? ar[1] : ar[0], n0i = cA ? ai[1] : ai[0];
        float n1r = cA ? ar[0] : ar[1], n1i = cA ? ai[0] : ai[1];
        float n2r = cB ? ar[3] : ar[2], n2i = cB ? ai[3] : ai[2];
        float n3r = cB ? ar[2] : ar[3], n3i = cB ? ai[2] : ai[3];
        ar[0] = n0r; ai[0] = n0i; ar[1] = n1r; ai[1] = n1i;
        ar[2] = n2r; ai[2] = n2i; ar[3] = n3r; ai[3] = n3i;
    }
}

// ---------------------------------------------------------------------------
// Fully fused kernel: one block per batch element b. 1024 threads = 16 waves.
// Phase 1: x-projection for all 128 steps -> LDS (parallel across waves).
// Phase 2: serial LSTM scan on lanes 0..31 of wave 0 -> angles in LDS.
// Phase 3: QFC statevector + measure + head + log_softmax, 8 rows per wave.
// ALL float tensors are float32 (per reference dtypes); sentence int32.
// NO workspace use.
// ---------------------------------------------------------------------------
__global__ __launch_bounds__(1024) void k_fused(
    const float* __restrict__ emb,
    const int* __restrict__ sentence,
    const float* __restrict__ Win,
    const float* __restrict__ b_in,
    const float* __restrict__ phi,
    const float* __restrict__ Wout,
    const float* __restrict__ b_out,
    const float* __restrict__ phiq,
    const float* __restrict__ Whead,
    const float* __restrict__ b_head,
    float* __restrict__ out,
    QOps ops)
{
    __shared__ float zxs[S_][32];    // x-part of gate preactivations, 16 KB
    __shared__ float sang[S_][8];    // LSTM outputs (QFC input angles), 4 KB

    const int t    = threadIdx.x;
    const int wave = t >> 6;
    const int lane = t & 63;
    const int half = lane >> 5;
    const int l    = lane & 31;
    const int b    = blockIdx.x;

    // ---- Phase 1: z_x[s][l] = (b_in+phi)[l] + emb[tok_s] . Win[l,:64] ----
    {
        float wx[64];
        #pragma unroll
        for (int f = 0; f < 64; f++)
            wx[f] = Win[l * FAN_ + f];
        const float cb = b_in[l] + phi[l];

        #pragma unroll
        for (int i = 0; i < 4; i++) {
            const int s   = wave * 8 + i * 2 + half;   // 2 steps per wave-pass
            const int tok = sentence[s * B_ + b];
            float xlo = emb[tok * E_ + l];
            float xhi = emb[tok * E_ + 32 + l];
            float z0 = cb, z1 = 0.f, z2 = 0.f, z3 = 0.f;
            #pragma unroll
            for (int f = 0; f < 32; f += 4) {
                z0 = fmaf(__shfl(xlo, f + 0, 32), wx[f + 0], z0);
                z1 = fmaf(__shfl(xlo, f + 1, 32), wx[f + 1], z1);
                z2 = fmaf(__shfl(xlo, f + 2, 32), wx[f + 2], z2);
                z3 = fmaf(__shfl(xlo, f + 3, 32), wx[f + 3], z3);
            }
            #pragma unroll
            for (int f = 0; f < 32; f += 4) {
                z0 = fmaf(__shfl(xhi, f + 0, 32), wx[32 + f + 0], z0);
                z1 = fmaf(__shfl(xhi, f + 1, 32), wx[32 + f + 1], z1);
                z2 = fmaf(__shfl(xhi, f + 2, 32), wx[32 + f + 2], z2);
                z3 = fmaf(__shfl(xhi, f + 3, 32), wx[32 + f + 3], z3);
            }
            zxs[s][l] = (z0 + z1) + (z2 + z3);
        }
    }
    __syncthreads();

    // ---- Phase 2: serial LSTM scan (lanes 0..31 of wave 0) ----
    if (t < 32) {
        const int g = t >> 3;
        const int h = t & 7;
        float wh[8], wo[8];
        #pragma unroll
        for (int k = 0; k < 8; k++)
            wh[k] = Win[t * FAN_ + 64 + k];
        #pragma unroll
        for (int k = 0; k < 8; k++)
            wo[k] = Wout[(g * 8 + h) * 8 + k];
        const float bo = b_out[g * 8 + h];

        float hx[8];
        #pragma unroll
        for (int k = 0; k < 8; k++) hx[k] = 0.f;
        float cx = 0.f;

        for (int s = 0; s < S_; s++) {
            float z = zxs[s][t];
            #pragma unroll
            for (int k = 0; k < 8; k++) z = fmaf(wh[k], hx[k], z);

            float qc = __cosf(z);
            #pragma unroll
            for (int d = 1; d < 8; d <<= 1) {       // cumprod over q
                float u = __shfl_up(qc, d, 8);
                if ((t & 7) >= d) qc *= u;
            }
            float pre = bo;                          // pre[g,h] at lane (g,h)
            #pragma unroll
            for (int qq = 0; qq < 8; qq++)
                pre = fmaf(wo[qq], __shfl(qc, (t & 24) | qq, 32), pre);

            float p0 = __shfl(pre, h, 32);
            float p1 = __shfl(pre, 8 + h, 32);
            float p2 = __shfl(pre, 16 + h, 32);
            float p3 = __shfl(pre, 24 + h, 32);

            float f_ = sigmoid_f(p0);
            float i_ = sigmoid_f(p1);
            float g_ = tanh_f(p2);
            float o_ = sigmoid_f(p3);
            cx = f_ * cx + i_ * g_;
            float hnew = o_ * tanh_f(cx);

            if (t < 8) sang[s][t] = hnew;
            #pragma unroll
            for (int k = 0; k < 8; k++) hx[k] = __shfl(hnew, k, 32);
        }
    }
    __syncthreads();

    // ---- Phase 3: QFC + measure + head + log_softmax, 8 rows per wave ----
    for (int r = 0; r < 8; r++) {
        const int s = wave * 8 + r;

        float ar[4], ai[4];
        {   // product-state init: RY(theta_w) on |0...0>
            float P = 1.f, c6 = 0.f, s6 = 0.f, c7 = 0.f, s7 = 0.f;
            #pragma unroll
            for (int w = 0; w < 8; w++) {
                float th = sang[s][w] * 0.5f;
                float cw = __cosf(th);
                float sw = __sinf(th);
                if (w < 6)       P *= ((lane >> (5 - w)) & 1) ? sw : cw;
                else if (w == 6) { c6 = cw; s6 = sw; }
                else             { c7 = cw; s7 = sw; }
            }
            ar[0] = P * c6 * c7; ar[1] = P * c6 * s7;
            ar[2] = P * s6 * c7; ar[3] = P * s6 * s7;
            ai[0] = ai[1] = ai[2] = ai[3] = 0.f;
        }

        for (int i = 0; i < NOPS_; i++) {
            int ty = ops.type[i];
            int w  = ops.w1[i];
            if (ty == 3)      apply_cnot(w, ops.w2[i], lane, ar, ai);
            else if (ty == 2) apply_rz(w, ops.c0[i], ops.c1[i], lane, ar, ai);
            else              apply_rot_any(ty, w, ops.c0[i], ops.c1[i], lane, ar, ai);
        }

        #pragma unroll
        for (int w = 0; w < 8; w++) {   // trailing RX(phiq[w])
            float th = phiq[w] * 0.5f;
            apply_rot_any(0, w, __cosf(th), __sinf(th), lane, ar, ai);
        }

        // measure <Z_w>
        float p0 = ar[0] * ar[0] + ai[0] * ai[0];
        float p1 = ar[1] * ar[1] + ai[1] * ai[1];
        float p2 = ar[2] * ar[2] + ai[2] * ai[2];
        float p3 = ar[3] * ar[3] + ai[3] * ai[3];
        float pt = p0 + p1 + p2 + p3;
        float zl[8];
        #pragma unroll
        for (int w = 0; w < 6; w++)
            zl[w] = ((lane >> (5 - w)) & 1) ? -pt : pt;
        zl[6] = p0 + p1 - p2 - p3;
        zl[7] = p0 - p1 + p2 - p3;
        #pragma unroll
        for (int m = 1; m < 64; m <<= 1) {
            #pragma unroll
            for (int w = 0; w < 8; w++)
                zl[w] += __shfl_xor(zl[w], m, 64);
        }

        // head + log_softmax over 12 logits (lanes 0..11)
        float logit = -1e30f;
        if (lane < T_) {
            logit = b_head[lane];
            #pragma unroll
            for (int w = 0; w < 8; w++)
                logit = fmaf(zl[w], Whead[lane * 8 + w], logit);
        }
        float mx = logit;
        #pragma unroll
        for (int m = 1; m < 16; m <<= 1)
            mx = fmaxf(mx, __shfl_xor(mx, m, 16));
        float e = (lane < T_) ? __expf(logit - mx) : 0.f;
        float se = e;
        #pragma unroll
        for (int m = 1; m < 16; m <<= 1)
            se += __shfl_xor(se, m, 16);
        if (lane < T_)
            out[(b * S_ + s) * T_ + lane] = logit - mx - __logf(se);
    }
}

// ---------------------------------------------------------------------------
extern "C" void kernel_launch(void* const* d_in, const int* in_sizes, int n_in,
                              void* d_out, int out_size, void* d_ws, size_t ws_size,
                              hipStream_t stream)
{
    (void)in_sizes; (void)n_in; (void)out_size; (void)d_ws; (void)ws_size;
    const float* emb    = (const float*)d_in[0];
    const float* Win    = (const float*)d_in[1];
    const float* b_in   = (const float*)d_in[2];
    const float* phi    = (const float*)d_in[3];
    const float* Wout   = (const float*)d_in[4];
    const float* b_out  = (const float*)d_in[5];
    const float* phiq   = (const float*)d_in[6];
    const float* Whead  = (const float*)d_in[7];
    const float* b_head = (const float*)d_in[8];
    const int* sentence = (const int*)d_in[9];
    float* out          = (float*)d_out;

    static QOps ops = make_ops();   // deterministic; identical every call

    hipLaunchKernelGGL(k_fused, dim3(B_), dim3(1024), 0, stream,
                       emb, sentence, Win, b_in, phi, Wout, b_out,
                       phiq, Whead, b_head, out, ops);
}

// Round 5
// 240.012 us; speedup vs baseline: 1.0735x; 1.0735x over previous
//
#include <hip/hip_runtime.h>
#include <math.h>
#include <stdint.h>
#include <vector>

#ifndef M_PI
#define M_PI 3.14159265358979323846
#endif

#define S_    128
#define B_    128
#define E_    64
#define H_    8
#define T_    12
#define FAN_  72
#define NOPS_ 30
#define MAXG_ 30

// ---------------------------------------------------------------------------
// numpy.random.RandomState(1234) legacy stream (validated round 4).
// ---------------------------------------------------------------------------
struct MT19937 {
    uint32_t mt[624];
    int idx;
    void seed(uint32_t s) {
        for (int i = 0; i < 624; i++) {
            mt[i] = s;
            s = 1812433253u * (s ^ (s >> 30)) + (uint32_t)i + 1u;
        }
        idx = 624;
    }
    uint32_t next() {
        if (idx >= 624) {
            for (int i = 0; i < 624; i++) {
                uint32_t y = (mt[i] & 0x80000000u) | (mt[(i + 1) % 624] & 0x7fffffffu);
                uint32_t v = mt[(i + 397) % 624] ^ (y >> 1);
                mt[i] = (y & 1u) ? (v ^ 0x9908b0dfu) : v;
            }
            idx = 0;
        }
        uint32_t y = mt[idx++];
        y ^= y >> 11;
        y ^= (y << 7)  & 0x9d2c5680u;
        y ^= (y << 15) & 0xefc60000u;
        y ^= y >> 18;
        return y;
    }
    uint32_t randint(uint32_t n) {
        uint32_t rng = n - 1u, mask = rng;
        mask |= mask >> 1; mask |= mask >> 2; mask |= mask >> 4;
        mask |= mask >> 8; mask |= mask >> 16;
        uint32_t v;
        do { v = next() & mask; } while (v > rng);
        return v;
    }
    double uniform(double lo, double hi) {
        uint32_t a = next() >> 5, b = next() >> 6;
        double d = ((double)a * 67108864.0 + (double)b) / 9007199254740992.0;
        return lo + (hi - lo) * d;
    }
};

// ---------------------------------------------------------------------------
// Host-side circuit optimizer: leading-fold, commuting merges, CNOT cancel,
// trailing extraction. All single-qubit gates become generic 2x2 complex.
// ---------------------------------------------------------------------------
struct C2h { double r, i; };
static inline C2h cmul(C2h a, C2h b) { return { a.r*b.r - a.i*b.i, a.r*b.i + a.i*b.r }; }
static inline C2h cadd(C2h a, C2h b) { return { a.r + b.r, a.i + b.i }; }
struct M22 { C2h m[2][2]; };
static inline M22 mmul(const M22& A, const M22& B) {  // A*B (A applied after B)
    M22 C;
    for (int i = 0; i < 2; i++)
        for (int j = 0; j < 2; j++)
            C.m[i][j] = cadd(cmul(A.m[i][0], B.m[0][j]), cmul(A.m[i][1], B.m[1][j]));
    return C;
}
static inline M22 ident() { return { { { {1,0},{0,0} }, { {0,0},{1,0} } } }; }

struct HostOp { int kind; int a, b; M22 U; };  // kind 0=gate1(wire a), 1=cnot(a,b)

struct QCircuit {
    int   n;
    int   type[MAXG_];   // 0 gate1, 1 cnot
    int   w1[MAXG_];     // wire / control
    int   w2[MAXG_];     // target
    float U[MAXG_][8];   // [00r,00i,01r,01i,10r,10i,11r,11i]
    float initM[8][8];
    float endM[8][8];
};

static void putM(float* dst, const M22& M) {
    dst[0] = (float)M.m[0][0].r; dst[1] = (float)M.m[0][0].i;
    dst[2] = (float)M.m[0][1].r; dst[3] = (float)M.m[0][1].i;
    dst[4] = (float)M.m[1][0].r; dst[5] = (float)M.m[1][0].i;
    dst[6] = (float)M.m[1][1].r; dst[7] = (float)M.m[1][1].i;
}

static QCircuit build_circuit() {
    MT19937 rng; rng.seed(1234u);
    std::vector<HostOp> raw;
    for (int i = 0; i < NOPS_; i++) {
        uint32_t kind = rng.randint(4);
        if (kind == 3u) {
            int c = (int)rng.randint(8);
            int t = (int)rng.randint(7);
            if (t >= c) t += 1;
            raw.push_back({1, c, t, ident()});
        } else {
            int g = (int)(kind % 3u);
            int w = (int)rng.randint(8);
            double th = rng.uniform(0.0, 2.0 * M_PI);
            double c = cos(0.5 * th), s = sin(0.5 * th);
            M22 M;
            if (g == 0)      M = { { { {c,0},{0,-s} }, { {0,-s},{c,0} } } };   // rx
            else if (g == 1) M = { { { {c,0},{-s,0} }, { {s,0},{c,0} } } };    // ry
            else             M = { { { {c,-s},{0,0} }, { {0,0},{c,s} } } };    // rz
            raw.push_back({0, w, -1, M});
        }
    }

    std::vector<HostOp> items;
    M22 initM[8], endM[8];
    for (int w = 0; w < 8; w++) { initM[w] = ident(); endM[w] = ident(); }

    for (const HostOp& op : raw) {
        if (op.kind == 0) {
            int w = op.a, k = (int)items.size() - 1;
            bool merged = false;
            while (k >= 0) {
                if (items[k].kind == 0) {
                    if (items[k].a == w) { items[k].U = mmul(op.U, items[k].U); merged = true; break; }
                    k--;
                } else {
                    if (w == items[k].a || w == items[k].b) break;
                    k--;
                }
            }
            if (merged) continue;
            if (k < 0) { initM[w] = mmul(op.U, initM[w]); continue; }
            items.push_back(op);
        } else {
            int c = op.a, t = op.b, k = (int)items.size() - 1;
            bool cancelled = false;
            while (k >= 0) {
                if (items[k].kind == 0) {
                    int w = items[k].a;
                    if (w == c || w == t) break;
                    k--;
                } else {
                    int c2 = items[k].a, t2 = items[k].b;
                    if (c2 == c && t2 == t) { items.erase(items.begin() + k); cancelled = true; break; }
                    if (c2 != t && t2 != c) k--;
                    else break;
                }
            }
            if (!cancelled) items.push_back(op);
        }
    }
    // trailing extraction
    bool blocked[8] = {};
    for (int k = (int)items.size() - 1; k >= 0; k--) {
        if (items[k].kind == 0) {
            int w = items[k].a;
            if (!blocked[w]) {
                endM[w] = mmul(endM[w], items[k].U);
                items.erase(items.begin() + k);
            }
        } else {
            blocked[items[k].a] = blocked[items[k].b] = true;
        }
    }

    QCircuit q = {};
    q.n = (int)items.size();
    for (int i = 0; i < q.n; i++) {
        q.type[i] = items[i].kind;
        q.w1[i]   = items[i].a;
        q.w2[i]   = items[i].b;
        putM(q.U[i], items[i].U);
    }
    for (int w = 0; w < 8; w++) { putM(q.initM[w], initM[w]); putM(q.endM[w], endM[w]); }
    return q;
}

// ---------------------------------------------------------------------------
// Device helpers
// ---------------------------------------------------------------------------
__device__ __forceinline__ float sigmoid_f(float x) { return 1.f / (1.f + __expf(-x)); }
__device__ __forceinline__ float tanh_f(float x) {
    float e = __expf(2.f * x);
    return 1.f - 2.f / (e + 1.f);
}

template<int CTRL>
__device__ __forceinline__ float dppf(float x) {
    union { float f; int i; } u, r;
    u.f = x;
    r.i = __builtin_amdgcn_update_dpp(0, u.i, CTRL, 0xF, 0xF, true);
    return r.f;
}

// lane-xor exchange by mask M (DPP where possible, DS for 16/32)
template<int M>
__device__ __forceinline__ float lane_xor(float x, int lane) {
    if constexpr (M == 1)  return dppf<0xB1>(x);                 // quad_perm [1,0,3,2]
    else if constexpr (M == 2) return dppf<0x4E>(x);             // quad_perm [2,3,0,1]
    else if constexpr (M == 4) {
        float a = dppf<0x104>(x);   // row_shl:4  (lane+4)
        float b = dppf<0x114>(x);   // row_shr:4  (lane-4)
        return (lane & 4) ? b : a;
    }
    else if constexpr (M == 8) return dppf<0x128>(x);            // row_ror:8 == xor8
    else return __shfl_xor(x, M, 64);
}

// wire w (0..5) -> xor mask 1<<(5-w)
template<int W>
__device__ __forceinline__ float exch(float x, int lane) {
    if constexpr (W == 0) return __shfl_xor(x, 32, 64);
    else if constexpr (W == 1) return __shfl_xor(x, 16, 64);
    else if constexpr (W == 2) return lane_xor<8>(x, lane);
    else if constexpr (W == 3) return lane_xor<4>(x, lane);
    else if constexpr (W == 4) return lane_xor<2>(x, lane);
    else return lane_xor<1>(x, lane);
}

__device__ __forceinline__ int qbit(int w, int lane, int j) {
    if (w < 6) return (lane >> (5 - w)) & 1;
    if (w == 6) return (j >> 1) & 1;
    return j & 1;
}

// generic single-qubit gate on lane-wire W
template<int W>
__device__ __forceinline__ void applyU_lane(const float* __restrict__ U, int lane,
                                            float ar[4], float ai[4]) {
    const int b = (lane >> (5 - W)) & 1;
    const float dr  = b ? U[6] : U[0];
    const float di  = b ? U[7] : U[1];
    const float onr = b ? U[4] : U[2];
    const float oni = b ? U[5] : U[3];
    #pragma unroll
    for (int j = 0; j < 4; j++) {
        float br = exch<W>(ar[j], lane);
        float bi = exch<W>(ai[j], lane);
        float nr = dr * ar[j] - di * ai[j] + onr * br - oni * bi;
        float ni = dr * ai[j] + di * ar[j] + onr * bi + oni * br;
        ar[j] = nr; ai[j] = ni;
    }
}

// generic single-qubit gate on a register pair
__device__ __forceinline__ void applyU_pair(const float* __restrict__ U,
    float& a0r, float& a0i, float& a1r, float& a1i) {
    float n0r = U[0]*a0r - U[1]*a0i + U[2]*a1r - U[3]*a1i;
    float n0i = U[0]*a0i + U[1]*a0r + U[2]*a1i + U[3]*a1r;
    float n1r = U[4]*a0r - U[5]*a0i + U[6]*a1r - U[7]*a1i;
    float n1i = U[4]*a0i + U[5]*a0r + U[6]*a1i + U[7]*a1r;
    a0r = n0r; a0i = n0i; a1r = n1r; a1i = n1i;
}

__device__ __forceinline__ void applyU_any(int w, const float* __restrict__ U, int lane,
                                           float ar[4], float ai[4]) {
    switch (w) {
        case 0: applyU_lane<0>(U, lane, ar, ai); break;
        case 1: applyU_lane<1>(U, lane, ar, ai); break;
        case 2: applyU_lane<2>(U, lane, ar, ai); break;
        case 3: applyU_lane<3>(U, lane, ar, ai); break;
        case 4: applyU_lane<4>(U, lane, ar, ai); break;
        case 5: applyU_lane<5>(U, lane, ar, ai); break;
        case 6: applyU_pair(U, ar[0], ai[0], ar[2], ai[2]);
                applyU_pair(U, ar[1], ai[1], ar[3], ai[3]); break;
        default:applyU_pair(U, ar[0], ai[0], ar[1], ai[1]);
                applyU_pair(U, ar[2], ai[2], ar[3], ai[3]); break;
    }
}

template<int TW>
__device__ __forceinline__ void cnot_lane(int cw, int lane, float ar[4], float ai[4]) {
    #pragma unroll
    for (int j = 0; j < 4; j++) {
        float br = exch<TW>(ar[j], lane);
        float bi = exch<TW>(ai[j], lane);
        int ctrl = qbit(cw, lane, j);
        ar[j] = ctrl ? br : ar[j];
        ai[j] = ctrl ? bi : ai[j];
    }
}

__device__ __forceinline__ void apply_cnot(int cw, int tw, int lane,
                                           float ar[4], float ai[4]) {
    if (tw < 6) {
        switch (tw) {
            case 0: cnot_lane<0>(cw, lane, ar, ai); break;
            case 1: cnot_lane<1>(cw, lane, ar, ai); break;
            case 2: cnot_lane<2>(cw, lane, ar, ai); break;
            case 3: cnot_lane<3>(cw, lane, ar, ai); break;
            case 4: cnot_lane<4>(cw, lane, ar, ai); break;
            default:cnot_lane<5>(cw, lane, ar, ai); break;
        }
    } else if (tw == 6) {
        int cA = qbit(cw, lane, 0), cB = qbit(cw, lane, 1);
        float n0r = cA ? ar[2] : ar[0], n0i = cA ? ai[2] : ai[0];
        float n2r = cA ? ar[0] : ar[2], n2i = cA ? ai[0] : ai[2];
        float n1r = cB ? ar[3] : ar[1], n1i = cB ? ai[3] : ai[1];
        float n3r = cB ? ar[1] : ar[3], n3i = cB ? ai[1] : ai[3];
        ar[0]=n0r; ai[0]=n0i; ar[1]=n1r; ai[1]=n1i;
        ar[2]=n2r; ai[2]=n2i; ar[3]=n3r; ai[3]=n3i;
    } else {
        int cA = qbit(cw, lane, 0), cB = qbit(cw, lane, 2);
        float n0r = cA ? ar[1] : ar[0], n0i = cA ? ai[1] : ai[0];
        float n1r = cA ? ar[0] : ar[1], n1i = cA ? ai[0] : ai[1];
        float n2r = cB ? ar[3] : ar[2], n2i = cB ? ai[3] : ai[2];
        float n3r = cB ? ar[2] : ar[3], n3i = cB ? ai[2] : ai[3];
        ar[0]=n0r; ai[0]=n0i; ar[1]=n1r; ai[1]=n1i;
        ar[2]=n2r; ai[2]=n2i; ar[3]=n3r; ai[3]=n3i;
    }
}

// DPP all-gather of 8 values within each 8-lane group (value v at lane j)
__device__ __forceinline__ void bcast8(float v, int lane, float h[8]) {
    float p  = lane_xor<1>(v, lane);
    float a0 = (lane & 1) ? p : v;
    float a1 = (lane & 1) ? v : p;
    float q0 = lane_xor<2>(a0, lane);
    float q1 = lane_xor<2>(a1, lane);
    float b0 = (lane & 2) ? q0 : a0;
    float b1 = (lane & 2) ? q1 : a1;
    float b2 = (lane & 2) ? a0 : q0;
    float b3 = (lane & 2) ? a1 : q1;
    float r0 = lane_xor<4>(b0, lane);
    float r1 = lane_xor<4>(b1, lane);
    float r2 = lane_xor<4>(b2, lane);
    float r3 = lane_xor<4>(b3, lane);
    h[0] = (lane & 4) ? r0 : b0;  h[1] = (lane & 4) ? r1 : b1;
    h[2] = (lane & 4) ? r2 : b2;  h[3] = (lane & 4) ? r3 : b3;
    h[4] = (lane & 4) ? b0 : r0;  h[5] = (lane & 4) ? b1 : r1;
    h[6] = (lane & 4) ? b2 : r2;  h[7] = (lane & 4) ? b3 : r3;
}

// ---------------------------------------------------------------------------
// Fused kernel. 256 blocks x 1024 threads. blockIdx: b = idx>>1, half = idx&1.
// Phase 1: x-projection -> LDS. Phase 2: serial LSTM (lanes 0..31) -> angles.
// Phase 3: QFC statevector for this half's 64 rows (4 rows per wave).
// ---------------------------------------------------------------------------
__global__ __launch_bounds__(1024) void k_fused(
    const float* __restrict__ emb,
    const int* __restrict__ sentence,
    const float* __restrict__ Win,
    const float* __restrict__ b_in,
    const float* __restrict__ phi,
    const float* __restrict__ Wout,
    const float* __restrict__ b_out,
    const float* __restrict__ phiq,
    const float* __restrict__ Whead,
    const float* __restrict__ b_head,
    float* __restrict__ out,
    const QCircuit circ)
{
    __shared__ float zxs[S_][32];
    __shared__ float sang[S_][8];
    __shared__ float sF[8][8];
    __shared__ QCircuit sCirc;

    const int t     = threadIdx.x;
    const int wave  = t >> 6;
    const int lane  = t & 63;
    const int half  = lane >> 5;
    const int l     = lane & 31;
    const int b     = blockIdx.x >> 1;
    const int half3 = blockIdx.x & 1;

    // copy circuit into LDS (avoid scratch from dynamic kernarg indexing)
    {
        const int nwords = (int)(sizeof(QCircuit) / 4);
        const int* src = (const int*)&circ;
        int* dst = (int*)&sCirc;
        for (int k = t; k < nwords; k += 1024) dst[k] = src[k];
    }

    // ---- Phase 1: z_x[s][l] = (b_in+phi)[l] + emb[tok_s] . Win[l,:64] ----
    {
        float wx[64];
        #pragma unroll
        for (int f = 0; f < 64; f++)
            wx[f] = Win[l * FAN_ + f];
        const float cb = b_in[l] + phi[l];

        #pragma unroll
        for (int i = 0; i < 4; i++) {
            const int s   = wave * 8 + i * 2 + half;
            const int tok = sentence[s * B_ + b];
            const float4* e4 = (const float4*)(emb + tok * E_);
            float z0 = cb, z1 = 0.f, z2 = 0.f, z3 = 0.f;
            #pragma unroll
            for (int f = 0; f < 16; f++) {
                float4 xv = e4[f];          // same addr across lanes: broadcast
                z0 = fmaf(xv.x, wx[4*f + 0], z0);
                z1 = fmaf(xv.y, wx[4*f + 1], z1);
                z2 = fmaf(xv.z, wx[4*f + 2], z2);
                z3 = fmaf(xv.w, wx[4*f + 3], z3);
            }
            zxs[s][l] = (z0 + z1) + (z2 + z3);
        }
    }

    // waves 1: compute final per-wire gates F_w = RX(phiq_w) * endM_w into LDS
    if (t >= 64 && t < 72) {
        const int w = t - 64;
        const float* E = sCirc.endM[w];   // careful: sCirc copy done by this thread's strides? barrier below protects readers, but E read now...
        // read from kernarg directly instead (constant index would be needed);
        // safest: read from the by-value circ with runtime w via small local copy:
        float Ew[8];
        #pragma unroll
        for (int k = 0; k < 8; k++) Ew[k] = circ.endM[w][k];
        (void)E;
        float ph = phiq[w] * 0.5f;
        float c = __cosf(ph), s = __sinf(ph);
        sF[w][0] =  c*Ew[0] + s*Ew[5];
        sF[w][1] =  c*Ew[1] - s*Ew[4];
        sF[w][2] =  c*Ew[2] + s*Ew[7];
        sF[w][3] =  c*Ew[3] - s*Ew[6];
        sF[w][4] =  s*Ew[1] + c*Ew[4];
        sF[w][5] = -s*Ew[0] + c*Ew[5];
        sF[w][6] =  s*Ew[3] + c*Ew[6];
        sF[w][7] = -s*Ew[2] + c*Ew[7];
    }
    __syncthreads();

    // ---- Phase 2: serial LSTM scan (lanes 0..31 of wave 0) ----
    if (t < 32) {
        const int g = t >> 3;
        const int h = t & 7;
        const int q = t & 7;
        float wh[8], wo[8];
        #pragma unroll
        for (int k = 0; k < 8; k++) wh[k] = Win[t * FAN_ + 64 + k];
        #pragma unroll
        for (int k = 0; k < 8; k++) wo[k] = Wout[(g * 8 + h) * 8 + k];
        const float bo = b_out[g * 8 + h];

        float hxv[8];
        #pragma unroll
        for (int k = 0; k < 8; k++) hxv[k] = 0.f;
        float cx = 0.f;

        for (int s = 0; s < S_; s++) {
            float z = zxs[s][t];
            #pragma unroll
            for (int k = 0; k < 8; k++) z = fmaf(wh[k], hxv[k], z);

            float qc = __cosf(z);
            // inclusive cumprod over q via DPP row_shr (masked)
            float u1 = dppf<0x111>(qc); qc = (q >= 1) ? qc * u1 : qc;
            float u2 = dppf<0x112>(qc); qc = (q >= 2) ? qc * u2 : qc;
            float u4 = dppf<0x114>(qc); qc = (q >= 4) ? qc * u4 : qc;

            float pre = bo;
            #pragma unroll
            for (int qq = 0; qq < 8; qq++)
                pre = fmaf(wo[qq], __shfl(qc, (t & 24) | qq, 32), pre);

            float p0 = __shfl(pre, h, 32);
            float p1 = __shfl(pre, 8 + h, 32);
            float p2 = __shfl(pre, 16 + h, 32);
            float p3 = __shfl(pre, 24 + h, 32);

            float f_ = sigmoid_f(p0);
            float i_ = sigmoid_f(p1);
            float g_ = tanh_f(p2);
            float o_ = sigmoid_f(p3);
            cx = f_ * cx + i_ * g_;
            float hnew = o_ * tanh_f(cx);

            if (t < 8) sang[s][t] = hnew;
            bcast8(hnew, t, hxv);
        }
    }
    __syncthreads();

    // ---- Phase 3: QFC + measure + head + log_softmax, 4 rows per wave ----
    const int nops = circ.n;
    for (int r = 0; r < 4; r++) {
        const int s = half3 * 64 + wave * 4 + r;

        float ar[4], ai[4];
        {   // init: per-wire v_w = initM[w] . (cos, sin); product state
            float Pr = 1.f, Pi = 0.f;
            float v60r=0,v60i=0,v61r=0,v61i=0,v70r=0,v70i=0,v71r=0,v71i=0;
            #pragma unroll
            for (int w = 0; w < 8; w++) {
                float th = sang[s][w] * 0.5f;
                float c = __cosf(th), sn = __sinf(th);
                const float* M = sCirc.initM[w];
                float a0r = M[0]*c + M[2]*sn, a0i = M[1]*c + M[3]*sn;
                float a1r = M[4]*c + M[6]*sn, a1i = M[5]*c + M[7]*sn;
                if (w < 6) {
                    int bit = (lane >> (5 - w)) & 1;
                    float er = bit ? a1r : a0r;
                    float ei = bit ? a1i : a0i;
                    float nr = Pr * er - Pi * ei;
                    float ni = Pr * ei + Pi * er;
                    Pr = nr; Pi = ni;
                } else if (w == 6) { v60r=a0r; v60i=a0i; v61r=a1r; v61i=a1i; }
                else               { v70r=a0r; v70i=a0i; v71r=a1r; v71i=a1i; }
            }
            float t0r = Pr*v60r - Pi*v60i, t0i = Pr*v60i + Pi*v60r;
            float t1r = Pr*v61r - Pi*v61i, t1i = Pr*v61i + Pi*v61r;
            ar[0] = t0r*v70r - t0i*v70i;  ai[0] = t0r*v70i + t0i*v70r;
            ar[1] = t0r*v71r - t0i*v71i;  ai[1] = t0r*v71i + t0i*v71r;
            ar[2] = t1r*v70r - t1i*v70i;  ai[2] = t1r*v70i + t1i*v70r;
            ar[3] = t1r*v71r - t1i*v71i;  ai[3] = t1r*v71i + t1i*v71r;
        }

        // middle ops
        for (int i = 0; i < nops; i++) {
            if (sCirc.type[i] == 0) applyU_any(sCirc.w1[i], sCirc.U[i], lane, ar, ai);
            else                    apply_cnot(sCirc.w1[i], sCirc.w2[i], lane, ar, ai);
        }

        // final per-wire gates F_w (trailing rotations + RX(phiq))
        #pragma unroll
        for (int w = 0; w < 8; w++)
            applyU_any(w, sF[w], lane, ar, ai);

        // measure <Z_w> via Walsh-Hadamard on pt; plain sums for reg wires
        float p0 = ar[0]*ar[0] + ai[0]*ai[0];
        float p1 = ar[1]*ar[1] + ai[1]*ai[1];
        float p2 = ar[2]*ar[2] + ai[2]*ai[2];
        float p3 = ar[3]*ar[3] + ai[3]*ai[3];
        float pt = p0 + p1 + p2 + p3;
        float a6 = p0 + p1 - p2 - p3;
        float a7 = p0 - p1 + p2 - p3;

        {
            float tv;
            tv = lane_xor<1>(pt, lane);  pt = (lane & 1)  ? (tv - pt) : (tv + pt);
            tv = lane_xor<2>(pt, lane);  pt = (lane & 2)  ? (tv - pt) : (tv + pt);
            tv = lane_xor<4>(pt, lane);  pt = (lane & 4)  ? (tv - pt) : (tv + pt);
            tv = lane_xor<8>(pt, lane);  pt = (lane & 8)  ? (tv - pt) : (tv + pt);
            tv = lane_xor<16>(pt, lane); pt = (lane & 16) ? (tv - pt) : (tv + pt);
            tv = lane_xor<32>(pt, lane); pt = (lane & 32) ? (tv - pt) : (tv + pt);
            a6 += lane_xor<1>(a6, lane);  a6 += lane_xor<2>(a6, lane);
            a6 += lane_xor<4>(a6, lane);  a6 += lane_xor<8>(a6, lane);
            a6 += lane_xor<16>(a6, lane); a6 += lane_xor<32>(a6, lane);
            a7 += lane_xor<1>(a7, lane);  a7 += lane_xor<2>(a7, lane);
            a7 += lane_xor<4>(a7, lane);  a7 += lane_xor<8>(a7, lane);
            a7 += lane_xor<16>(a7, lane); a7 += lane_xor<32>(a7, lane);
        }
        float zl[8];
        zl[0] = __shfl(pt, 32, 64);
        zl[1] = __shfl(pt, 16, 64);
        zl[2] = __shfl(pt, 8, 64);
        zl[3] = __shfl(pt, 4, 64);
        zl[4] = __shfl(pt, 2, 64);
        zl[5] = __shfl(pt, 1, 64);
        zl[6] = a6;
        zl[7] = a7;

        // head + log_softmax over 12 logits (lanes 0..11, reduce within 16)
        float logit = -1e30f;
        if (lane < T_) {
            logit = b_head[lane];
            #pragma unroll
            for (int w = 0; w < 8; w++)
                logit = fmaf(zl[w], Whead[lane * 8 + w], logit);
        }
        float mx = logit;
        mx = fmaxf(mx, lane_xor<1>(mx, lane));
        mx = fmaxf(mx, lane_xor<2>(mx, lane));
        mx = fmaxf(mx, lane_xor<4>(mx, lane));
        mx = fmaxf(mx, lane_xor<8>(mx, lane));
        float e = (lane < T_) ? __expf(logit - mx) : 0.f;
        float se = e;
        se += lane_xor<1>(se, lane);
        se += lane_xor<2>(se, lane);
        se += lane_xor<4>(se, lane);
        se += lane_xor<8>(se, lane);
        if (lane < T_)
            out[(b * S_ + s) * T_ + lane] = logit - mx - __logf(se);
    }
}

// ---------------------------------------------------------------------------
extern "C" void kernel_launch(void* const* d_in, const int* in_sizes, int n_in,
                              void* d_out, int out_size, void* d_ws, size_t ws_size,
                              hipStream_t stream)
{
    (void)in_sizes; (void)n_in; (void)out_size; (void)d_ws; (void)ws_size;
    const float* emb    = (const float*)d_in[0];
    const float* Win    = (const float*)d_in[1];
    const float* b_in   = (const float*)d_in[2];
    const float* phi    = (const float*)d_in[3];
    const float* Wout   = (const float*)d_in[4];
    const float* b_out  = (const float*)d_in[5];
    const float* phiq   = (const float*)d_in[6];
    const float* Whead  = (const float*)d_in[7];
    const float* b_head = (const float*)d_in[8];
    const int* sentence = (const int*)d_in[9];
    float* out          = (float*)d_out;

    static QCircuit circ = build_circuit();   // deterministic; identical every call

    hipLaunchKernelGGL(k_fused, dim3(2 * B_), dim3(1024), 0, stream,
                       emb, sentence, Win, b_in, phi, Wout, b_out,
                       phiq, Whead, b_head, out, circ);
}